// Round 2
// baseline (43.365 us; speedup 1.0000x reference)
//
#include <hip/hip_runtime.h>
#include <hip/hip_cooperative_groups.h>

namespace cg = cooperative_groups;

// Problem constants (fixed by the reference's setup_inputs)
#define BB 8
#define NN 16
#define KK 128
#define HH 64
#define WW 64
#define HWPX (HH * WW)

// Single cooperative kernel: one block per (b, n) heatmap computes a partial
// triple (pos_loss, neg_loss, neg_count); grid.sync(); block 0 folds the 128
// triples into the scalar loss. 128 blocks x 128 threads — all co-resident
// (256 CUs), LDS 32.3 KB/block.
__global__ __launch_bounds__(128) void kp_loss_fused(
    const float* __restrict__ all_scores,   // [B, K, N]
    const float* __restrict__ gt_heatmap,   // [B, N, H, W]
    const float* __restrict__ keypoints,    // [B, K, 2] (row, col)
    float* __restrict__ partials,           // [B*N, 3] in d_ws
    float* __restrict__ out)                // [1]
{
    __shared__ float sh_r[HWPX];   // positive pixel rows (worst case all positive)
    __shared__ float sh_c[HWPX];   // positive pixel cols
    __shared__ int   sh_count;
    __shared__ float wred[2][3];   // per-wave partials (2 waves/block)

    const int blk  = blockIdx.x;       // b * N + n
    const int b    = blk >> 4;         // / NN
    const int n    = blk & (NN - 1);
    const int tid  = threadIdx.x;
    const int lane = tid & 63;
    const int wid  = tid >> 6;

    if (tid == 0) sh_count = 0;
    __syncthreads();

    // --- Phase 1: compact positive pixels into LDS (order irrelevant: min) ---
    // float4 reads; W=64 so a float4 never crosses a row boundary.
    const float4* hm = (const float4*)(gt_heatmap + (size_t)blk * HWPX);
    for (int i = tid; i < HWPX / 4; i += 128) {
        const float4 v = hm[i];
        const int base = i << 2;
        const float row = (float)(base >> 6);
        const float col = (float)(base & (WW - 1));
        if (v.x > 0.0f) { int s = atomicAdd(&sh_count, 1); sh_r[s] = row; sh_c[s] = col; }
        if (v.y > 0.0f) { int s = atomicAdd(&sh_count, 1); sh_r[s] = row; sh_c[s] = col + 1.0f; }
        if (v.z > 0.0f) { int s = atomicAdd(&sh_count, 1); sh_r[s] = row; sh_c[s] = col + 2.0f; }
        if (v.w > 0.0f) { int s = atomicAdd(&sh_count, 1); sh_r[s] = row; sh_c[s] = col + 3.0f; }
    }
    __syncthreads();
    const int cnt = sh_count;   // >= 1 (pixel (0,0) forced positive by setup)

    // --- Phase 2: thread tid owns keypoint tid ---
    const float kr = keypoints[((size_t)b * KK + tid) * 2 + 0];
    const float kc = keypoints[((size_t)b * KK + tid) * 2 + 1];
    float dmin2 = INFINITY;
    for (int m = 0; m < cnt; ++m) {
        const float dr = kr - sh_r[m];   // broadcast reads, no bank conflict
        const float dc = kc - sh_c[m];
        dmin2 = fminf(dmin2, dr * dr + dc * dc);
    }
    const float score = all_scores[((size_t)b * KK + tid) * NN + n];
    float r0 = 0.0f, r1 = 0.0f, r2 = 0.0f;
    if (dmin2 < 1.0f) {
        r0 = 10000.0f / (1.0f + __expf(sqrtf(dmin2))) * __logf(score);
    } else {
        r1 = __logf(1.0f - score);
        r2 = 1.0f;
    }

    // --- Phase 3: block-reduce the triple (shuffle within wave, LDS across) ---
    for (int off = 32; off > 0; off >>= 1) {
        r0 += __shfl_down(r0, off);
        r1 += __shfl_down(r1, off);
        r2 += __shfl_down(r2, off);
    }
    if (lane == 0) { wred[wid][0] = r0; wred[wid][1] = r1; wred[wid][2] = r2; }
    __syncthreads();
    if (tid == 0) {
        partials[blk * 3 + 0] = wred[0][0] + wred[1][0];
        partials[blk * 3 + 1] = wred[0][1] + wred[1][1];
        partials[blk * 3 + 2] = wred[0][2] + wred[1][2];
    }

    // --- Phase 4: grid-wide sync, block 0 finalizes ---
    cg::this_grid().sync();

    if (blk == 0) {
        float p0 = partials[tid * 3 + 0];
        float p1 = partials[tid * 3 + 1];
        float p2 = partials[tid * 3 + 2];
        for (int off = 32; off > 0; off >>= 1) {
            p0 += __shfl_down(p0, off);
            p1 += __shfl_down(p1, off);
            p2 += __shfl_down(p2, off);
        }
        if (lane == 0) { wred[wid][0] = p0; wred[wid][1] = p1; wred[wid][2] = p2; }
        __syncthreads();
        if (tid == 0) {
            const float pos_sum = wred[0][0] + wred[1][0];
            const float neg_sum = wred[0][1] + wred[1][1];
            const float cntf    = wred[0][2] + wred[1][2];
            float loss = -pos_sum;
            if (cntf > 0.0f) loss -= (10000.0f / cntf) * neg_sum;
            out[0] = loss;
        }
    }
}

extern "C" void kernel_launch(void* const* d_in, const int* in_sizes, int n_in,
                              void* d_out, int out_size, void* d_ws, size_t ws_size,
                              hipStream_t stream) {
    const float* all_scores = (const float*)d_in[0];  // [B, K, N]
    const float* gt_heatmap = (const float*)d_in[1];  // [B, N, H, W]
    const float* keypoints  = (const float*)d_in[2];  // [B, K, 2]
    float* out      = (float*)d_out;
    float* partials = (float*)d_ws;                   // 128 * 3 floats

    void* args[] = { (void*)&all_scores, (void*)&gt_heatmap, (void*)&keypoints,
                     (void*)&partials, (void*)&out };
    hipLaunchCooperativeKernel((void*)kp_loss_fused, dim3(BB * NN), dim3(128),
                               args, 0, stream);
}

// Round 3
// 16.068 us; speedup vs baseline: 2.6988x; 2.6988x over previous
//
#include <hip/hip_runtime.h>

// Problem constants (fixed by the reference's setup_inputs)
#define BB 8
#define NN 16
#define KK 128
#define HH 64
#define WW 64
#define HWPX (HH * WW)
#define NBLK (BB * NN)   // 128

// Workspace layout (floats): partials[3][128], then int counter at [384]
#define WS_P0 0
#define WS_P1 NBLK
#define WS_P2 (2 * NBLK)
#define WS_CNT_BYTE_OFF (3 * NBLK * sizeof(float))

// One block per (b, n) heatmap. Compact positive pixels into LDS, per-thread
// keypoint min, block-reduce the (pos_loss, neg_loss, neg_count) triple,
// publish it agent-scope, and let the LAST block to finish fold all 128
// triples into the scalar loss (no second kernel dispatch).
__global__ __launch_bounds__(128) void kp_loss_fused(
    const float* __restrict__ all_scores,   // [B, K, N]
    const float* __restrict__ gt_heatmap,   // [B, N, H, W]
    const float* __restrict__ keypoints,    // [B, K, 2] (row, col)
    float* __restrict__ ws,                 // workspace (see layout above)
    int*   __restrict__ done_cnt,           // zeroed by memset each launch
    float* __restrict__ out)                // [1]
{
    __shared__ float sh_r[HWPX];   // positive pixel rows (worst case: all)
    __shared__ float sh_c[HWPX];   // positive pixel cols
    __shared__ int   sh_count;
    __shared__ float wred[2][3];
    __shared__ int   sh_last;

    const int blk  = blockIdx.x;       // b * N + n
    const int b    = blk >> 4;
    const int n    = blk & (NN - 1);
    const int tid  = threadIdx.x;
    const int lane = tid & 63;
    const int wid  = tid >> 6;

    if (tid == 0) sh_count = 0;
    __syncthreads();

    // --- Phase 1: compact positive pixels (order irrelevant: we take a min) ---
    const float4* hm = (const float4*)(gt_heatmap + (size_t)blk * HWPX);
    for (int i = tid; i < HWPX / 4; i += 128) {
        const float4 v = hm[i];
        const int base = i << 2;
        const float row = (float)(base >> 6);
        const float col = (float)(base & (WW - 1));
        if (v.x > 0.0f) { int s = atomicAdd(&sh_count, 1); sh_r[s] = row; sh_c[s] = col; }
        if (v.y > 0.0f) { int s = atomicAdd(&sh_count, 1); sh_r[s] = row; sh_c[s] = col + 1.0f; }
        if (v.z > 0.0f) { int s = atomicAdd(&sh_count, 1); sh_r[s] = row; sh_c[s] = col + 2.0f; }
        if (v.w > 0.0f) { int s = atomicAdd(&sh_count, 1); sh_r[s] = row; sh_c[s] = col + 3.0f; }
    }
    __syncthreads();
    const int cnt = sh_count;   // >= 1 (pixel (0,0) forced positive by setup)

    // --- Phase 2: thread tid owns keypoint tid ---
    const float kr = keypoints[((size_t)b * KK + tid) * 2 + 0];
    const float kc = keypoints[((size_t)b * KK + tid) * 2 + 1];
    float dmin2 = INFINITY;
    for (int m = 0; m < cnt; ++m) {
        const float dr = kr - sh_r[m];   // broadcast reads: no bank conflicts
        const float dc = kc - sh_c[m];
        dmin2 = fminf(dmin2, dr * dr + dc * dc);
    }
    const float score = all_scores[((size_t)b * KK + tid) * NN + n];
    float r0 = 0.0f, r1 = 0.0f, r2 = 0.0f;
    if (dmin2 < 1.0f) {
        r0 = 10000.0f / (1.0f + __expf(sqrtf(dmin2))) * __logf(score);
    } else {
        r1 = __logf(1.0f - score);
        r2 = 1.0f;
    }

    // --- Phase 3: block-reduce the triple ---
    for (int off = 32; off > 0; off >>= 1) {
        r0 += __shfl_down(r0, off);
        r1 += __shfl_down(r1, off);
        r2 += __shfl_down(r2, off);
    }
    if (lane == 0) { wred[wid][0] = r0; wred[wid][1] = r1; wred[wid][2] = r2; }
    __syncthreads();

    // --- Phase 4: publish triple agent-scope; last finished block finalizes ---
    if (tid == 0) {
        __hip_atomic_store(&ws[WS_P0 + blk], wred[0][0] + wred[1][0],
                           __ATOMIC_RELAXED, __HIP_MEMORY_SCOPE_AGENT);
        __hip_atomic_store(&ws[WS_P1 + blk], wred[0][1] + wred[1][1],
                           __ATOMIC_RELAXED, __HIP_MEMORY_SCOPE_AGENT);
        __hip_atomic_store(&ws[WS_P2 + blk], wred[0][2] + wred[1][2],
                           __ATOMIC_RELAXED, __HIP_MEMORY_SCOPE_AGENT);
        const int old = __hip_atomic_fetch_add(done_cnt, 1, __ATOMIC_ACQ_REL,
                                               __HIP_MEMORY_SCOPE_AGENT);
        sh_last = (old == NBLK - 1);
    }
    __syncthreads();

    if (sh_last) {
        // all 127 other triples are visible (acq_rel on the counter)
        float p0 = __hip_atomic_load(&ws[WS_P0 + tid], __ATOMIC_RELAXED, __HIP_MEMORY_SCOPE_AGENT);
        float p1 = __hip_atomic_load(&ws[WS_P1 + tid], __ATOMIC_RELAXED, __HIP_MEMORY_SCOPE_AGENT);
        float p2 = __hip_atomic_load(&ws[WS_P2 + tid], __ATOMIC_RELAXED, __HIP_MEMORY_SCOPE_AGENT);
        for (int off = 32; off > 0; off >>= 1) {
            p0 += __shfl_down(p0, off);
            p1 += __shfl_down(p1, off);
            p2 += __shfl_down(p2, off);
        }
        if (lane == 0) { wred[wid][0] = p0; wred[wid][1] = p1; wred[wid][2] = p2; }
        __syncthreads();
        if (tid == 0) {
            const float pos_sum = wred[0][0] + wred[1][0];
            const float neg_sum = wred[0][1] + wred[1][1];
            const float cntf    = wred[0][2] + wred[1][2];
            float loss = -pos_sum;
            if (cntf > 0.0f) loss -= (10000.0f / cntf) * neg_sum;
            out[0] = loss;
        }
    }
}

extern "C" void kernel_launch(void* const* d_in, const int* in_sizes, int n_in,
                              void* d_out, int out_size, void* d_ws, size_t ws_size,
                              hipStream_t stream) {
    const float* all_scores = (const float*)d_in[0];  // [B, K, N]
    const float* gt_heatmap = (const float*)d_in[1];  // [B, N, H, W]
    const float* keypoints  = (const float*)d_in[2];  // [B, K, 2]
    float* out = (float*)d_out;
    float* ws  = (float*)d_ws;
    int* done_cnt = (int*)((char*)d_ws + WS_CNT_BYTE_OFF);

    // d_ws is poisoned 0xAA once before timing and never re-poisoned between
    // replays: the counter must be zeroed on every call.
    hipMemsetAsync(done_cnt, 0, sizeof(int), stream);
    kp_loss_fused<<<NBLK, 128, 0, stream>>>(all_scores, gt_heatmap, keypoints,
                                            ws, done_cnt, out);
}

// Round 4
// 11.409 us; speedup vs baseline: 3.8011x; 1.4085x over previous
//
#include <hip/hip_runtime.h>

// Problem constants (fixed by the reference's setup_inputs)
#define BB 8
#define NN 16
#define KK 128
#define HH 64
#define WW 64
#define HWPX (HH * WW)
#define NBLK (BB * NN)   // 128

// Workspace layout (floats): partials[3][128], then uint counter at [384].
// The counter is NEVER reset: each call adds exactly NBLK, so exactly one
// block per call sees old % NBLK == NBLK-1 — works from any initial value
// (0xAA poison included) and across graph replays. 128 divides 2^32 so
// wraparound is harmless.
#define WS_P0 0
#define WS_P1 NBLK
#define WS_P2 (2 * NBLK)
#define WS_CNT_BYTE_OFF (3 * NBLK * sizeof(float))

__global__ __launch_bounds__(128) void kp_loss_fused(
    const float* __restrict__ all_scores,   // [B, K, N]
    const float* __restrict__ gt_heatmap,   // [B, N, H, W]
    const float* __restrict__ keypoints,    // [B, K, 2] (row, col)
    float* __restrict__ ws,                 // workspace (see layout above)
    unsigned int* __restrict__ done_cnt,    // never reset (mod-NBLK check)
    float* __restrict__ out)                // [1]
{
    __shared__ float sh_r[HWPX];   // positive pixel rows (worst case: all)
    __shared__ float sh_c[HWPX];   // positive pixel cols
    __shared__ int   sh_count;
    __shared__ float wred[2][3];
    __shared__ int   sh_last;

    const int blk  = blockIdx.x;       // b * N + n
    const int b    = blk >> 4;
    const int n    = blk & (NN - 1);
    const int tid  = threadIdx.x;
    const int lane = tid & 63;
    const int wid  = tid >> 6;

    if (tid == 0) sh_count = 0;
    __syncthreads();

    // --- Phase 1: compact positive pixels (order irrelevant: we take a min) ---
    const float4* hm = (const float4*)(gt_heatmap + (size_t)blk * HWPX);
    for (int i = tid; i < HWPX / 4; i += 128) {
        const float4 v = hm[i];
        const int base = i << 2;
        const float row = (float)(base >> 6);
        const float col = (float)(base & (WW - 1));
        if (v.x > 0.0f) { int s = atomicAdd(&sh_count, 1); sh_r[s] = row; sh_c[s] = col; }
        if (v.y > 0.0f) { int s = atomicAdd(&sh_count, 1); sh_r[s] = row; sh_c[s] = col + 1.0f; }
        if (v.z > 0.0f) { int s = atomicAdd(&sh_count, 1); sh_r[s] = row; sh_c[s] = col + 2.0f; }
        if (v.w > 0.0f) { int s = atomicAdd(&sh_count, 1); sh_r[s] = row; sh_c[s] = col + 3.0f; }
    }
    __syncthreads();
    const int cnt = sh_count;   // >= 1 (pixel (0,0) forced positive by setup)

    // --- Phase 2: thread tid owns keypoint tid ---
    const float kr = keypoints[((size_t)b * KK + tid) * 2 + 0];
    const float kc = keypoints[((size_t)b * KK + tid) * 2 + 1];
    float dmin2 = INFINITY;
    for (int m = 0; m < cnt; ++m) {
        const float dr = kr - sh_r[m];   // broadcast reads: no bank conflicts
        const float dc = kc - sh_c[m];
        dmin2 = fminf(dmin2, dr * dr + dc * dc);
    }
    const float score = all_scores[((size_t)b * KK + tid) * NN + n];
    float r0 = 0.0f, r1 = 0.0f, r2 = 0.0f;
    if (dmin2 < 1.0f) {
        r0 = 10000.0f / (1.0f + __expf(sqrtf(dmin2))) * __logf(score);
    } else {
        r1 = __logf(1.0f - score);
        r2 = 1.0f;
    }

    // --- Phase 3: block-reduce the triple ---
    for (int off = 32; off > 0; off >>= 1) {
        r0 += __shfl_down(r0, off);
        r1 += __shfl_down(r1, off);
        r2 += __shfl_down(r2, off);
    }
    if (lane == 0) { wred[wid][0] = r0; wred[wid][1] = r1; wred[wid][2] = r2; }
    __syncthreads();

    // --- Phase 4: publish triple agent-scope; last finished block finalizes ---
    if (tid == 0) {
        __hip_atomic_store(&ws[WS_P0 + blk], wred[0][0] + wred[1][0],
                           __ATOMIC_RELAXED, __HIP_MEMORY_SCOPE_AGENT);
        __hip_atomic_store(&ws[WS_P1 + blk], wred[0][1] + wred[1][1],
                           __ATOMIC_RELAXED, __HIP_MEMORY_SCOPE_AGENT);
        __hip_atomic_store(&ws[WS_P2 + blk], wred[0][2] + wred[1][2],
                           __ATOMIC_RELAXED, __HIP_MEMORY_SCOPE_AGENT);
        const unsigned int old = __hip_atomic_fetch_add(done_cnt, 1u, __ATOMIC_ACQ_REL,
                                                        __HIP_MEMORY_SCOPE_AGENT);
        sh_last = ((old & (NBLK - 1)) == NBLK - 1);
    }
    __syncthreads();

    if (sh_last) {
        // acq on the counter makes all 127 other release-published triples visible
        float p0 = __hip_atomic_load(&ws[WS_P0 + tid], __ATOMIC_RELAXED, __HIP_MEMORY_SCOPE_AGENT);
        float p1 = __hip_atomic_load(&ws[WS_P1 + tid], __ATOMIC_RELAXED, __HIP_MEMORY_SCOPE_AGENT);
        float p2 = __hip_atomic_load(&ws[WS_P2 + tid], __ATOMIC_RELAXED, __HIP_MEMORY_SCOPE_AGENT);
        for (int off = 32; off > 0; off >>= 1) {
            p0 += __shfl_down(p0, off);
            p1 += __shfl_down(p1, off);
            p2 += __shfl_down(p2, off);
        }
        if (lane == 0) { wred[wid][0] = p0; wred[wid][1] = p1; wred[wid][2] = p2; }
        __syncthreads();
        if (tid == 0) {
            const float pos_sum = wred[0][0] + wred[1][0];
            const float neg_sum = wred[0][1] + wred[1][1];
            const float cntf    = wred[0][2] + wred[1][2];
            float loss = -pos_sum;
            if (cntf > 0.0f) loss -= (10000.0f / cntf) * neg_sum;
            out[0] = loss;
        }
    }
}

extern "C" void kernel_launch(void* const* d_in, const int* in_sizes, int n_in,
                              void* d_out, int out_size, void* d_ws, size_t ws_size,
                              hipStream_t stream) {
    const float* all_scores = (const float*)d_in[0];  // [B, K, N]
    const float* gt_heatmap = (const float*)d_in[1];  // [B, N, H, W]
    const float* keypoints  = (const float*)d_in[2];  // [B, K, 2]
    float* out = (float*)d_out;
    float* ws  = (float*)d_ws;
    unsigned int* done_cnt = (unsigned int*)((char*)d_ws + WS_CNT_BYTE_OFF);

    kp_loss_fused<<<NBLK, 128, 0, stream>>>(all_scores, gt_heatmap, keypoints,
                                            ws, done_cnt, out);
}

// Round 5
// 10.505 us; speedup vs baseline: 4.1279x; 1.0860x over previous
//
#include <hip/hip_runtime.h>

// Problem constants (fixed by the reference's setup_inputs)
#define BB 8
#define NN 16
#define KK 128
#define HH 64
#define WW 64
#define HWPX (HH * WW)
#define NBLK (BB * NN)   // 128

// Workspace layout (floats): partials[3][128], then uint counter at [384].
// The counter is NEVER reset: each call adds exactly NBLK, so exactly one
// block per call sees old % NBLK == NBLK-1 — works from any initial value
// (0xAA poison included) and across graph replays. 128 divides 2^32 so
// wraparound is harmless.
#define WS_P0 0
#define WS_P1 NBLK
#define WS_P2 (2 * NBLK)
#define WS_CNT_BYTE_OFF (3 * NBLK * sizeof(float))

__global__ __launch_bounds__(256) void kp_loss_fused(
    const float* __restrict__ all_scores,   // [B, K, N]
    const float* __restrict__ gt_heatmap,   // [B, N, H, W]
    const float* __restrict__ keypoints,    // [B, K, 2] (row, col)
    float* __restrict__ ws,                 // workspace (see layout above)
    unsigned int* __restrict__ done_cnt,    // never reset (mod-NBLK check)
    float* __restrict__ out)                // [1]
{
    __shared__ float sh_r[HWPX];   // positive pixel rows (worst case: all)
    __shared__ float sh_c[HWPX];   // positive pixel cols
    __shared__ int   sh_count;
    __shared__ float wred[2][3];
    __shared__ int   sh_last;

    const int blk  = blockIdx.x;       // b * N + n
    const int b    = blk >> 4;
    const int n    = blk & (NN - 1);
    const int tid  = threadIdx.x;
    const int lane = tid & 63;
    const int wid  = tid >> 6;

    if (tid == 0) sh_count = 0;
    __syncthreads();

    // --- Phase 1: compact positive pixels, 256 threads (4 float4 loads each,
    // shorter latency chain than 8). Order irrelevant: we only take a min. ---
    const float4* hm = (const float4*)(gt_heatmap + (size_t)blk * HWPX);
    #pragma unroll
    for (int it = 0; it < HWPX / 4 / 256; ++it) {
        const int i = tid + it * 256;
        const float4 v = hm[i];
        const int base = i << 2;
        const float row = (float)(base >> 6);
        const float col = (float)(base & (WW - 1));
        if (v.x > 0.0f) { int s = atomicAdd(&sh_count, 1); sh_r[s] = row; sh_c[s] = col; }
        if (v.y > 0.0f) { int s = atomicAdd(&sh_count, 1); sh_r[s] = row; sh_c[s] = col + 1.0f; }
        if (v.z > 0.0f) { int s = atomicAdd(&sh_count, 1); sh_r[s] = row; sh_c[s] = col + 2.0f; }
        if (v.w > 0.0f) { int s = atomicAdd(&sh_count, 1); sh_r[s] = row; sh_c[s] = col + 3.0f; }
    }
    __syncthreads();
    const int cnt = sh_count;   // >= 1 (pixel (0,0) forced positive by setup)

    // --- Phase 2: threads 0..127 each own one keypoint ---
    float r0 = 0.0f, r1 = 0.0f, r2 = 0.0f;
    if (tid < KK) {
        const float kr = keypoints[((size_t)b * KK + tid) * 2 + 0];
        const float kc = keypoints[((size_t)b * KK + tid) * 2 + 1];
        float dmin2 = INFINITY;
        for (int m = 0; m < cnt; ++m) {
            const float dr = kr - sh_r[m];   // broadcast reads: no bank conflicts
            const float dc = kc - sh_c[m];
            dmin2 = fminf(dmin2, dr * dr + dc * dc);
        }
        const float score = all_scores[((size_t)b * KK + tid) * NN + n];
        if (dmin2 < 1.0f) {
            r0 = 10000.0f / (1.0f + __expf(sqrtf(dmin2))) * __logf(score);
        } else {
            r1 = __logf(1.0f - score);
            r2 = 1.0f;
        }
    }

    // --- Phase 3: reduce the triple over waves 0,1 (waves 2,3 hold zeros) ---
    if (wid < 2) {
        for (int off = 32; off > 0; off >>= 1) {
            r0 += __shfl_down(r0, off);
            r1 += __shfl_down(r1, off);
            r2 += __shfl_down(r2, off);
        }
        if (lane == 0) { wred[wid][0] = r0; wred[wid][1] = r1; wred[wid][2] = r2; }
    }
    __syncthreads();

    // --- Phase 4: publish triple agent-scope; last finished block finalizes ---
    if (tid == 0) {
        __hip_atomic_store(&ws[WS_P0 + blk], wred[0][0] + wred[1][0],
                           __ATOMIC_RELAXED, __HIP_MEMORY_SCOPE_AGENT);
        __hip_atomic_store(&ws[WS_P1 + blk], wred[0][1] + wred[1][1],
                           __ATOMIC_RELAXED, __HIP_MEMORY_SCOPE_AGENT);
        __hip_atomic_store(&ws[WS_P2 + blk], wred[0][2] + wred[1][2],
                           __ATOMIC_RELAXED, __HIP_MEMORY_SCOPE_AGENT);
        const unsigned int old = __hip_atomic_fetch_add(done_cnt, 1u, __ATOMIC_ACQ_REL,
                                                        __HIP_MEMORY_SCOPE_AGENT);
        sh_last = ((old & (NBLK - 1)) == NBLK - 1);
    }
    __syncthreads();

    if (sh_last) {
        // acq on the counter makes all 127 other release-published triples visible
        float p0 = 0.0f, p1 = 0.0f, p2 = 0.0f;
        if (tid < NBLK) {
            p0 = __hip_atomic_load(&ws[WS_P0 + tid], __ATOMIC_RELAXED, __HIP_MEMORY_SCOPE_AGENT);
            p1 = __hip_atomic_load(&ws[WS_P1 + tid], __ATOMIC_RELAXED, __HIP_MEMORY_SCOPE_AGENT);
            p2 = __hip_atomic_load(&ws[WS_P2 + tid], __ATOMIC_RELAXED, __HIP_MEMORY_SCOPE_AGENT);
        }
        if (wid < 2) {
            for (int off = 32; off > 0; off >>= 1) {
                p0 += __shfl_down(p0, off);
                p1 += __shfl_down(p1, off);
                p2 += __shfl_down(p2, off);
            }
            if (lane == 0) { wred[wid][0] = p0; wred[wid][1] = p1; wred[wid][2] = p2; }
        }
        __syncthreads();
        if (tid == 0) {
            const float pos_sum = wred[0][0] + wred[1][0];
            const float neg_sum = wred[0][1] + wred[1][1];
            const float cntf    = wred[0][2] + wred[1][2];
            float loss = -pos_sum;
            if (cntf > 0.0f) loss -= (10000.0f / cntf) * neg_sum;
            out[0] = loss;
        }
    }
}

extern "C" void kernel_launch(void* const* d_in, const int* in_sizes, int n_in,
                              void* d_out, int out_size, void* d_ws, size_t ws_size,
                              hipStream_t stream) {
    const float* all_scores = (const float*)d_in[0];  // [B, K, N]
    const float* gt_heatmap = (const float*)d_in[1];  // [B, N, H, W]
    const float* keypoints  = (const float*)d_in[2];  // [B, K, 2]
    float* out = (float*)d_out;
    float* ws  = (float*)d_ws;
    unsigned int* done_cnt = (unsigned int*)((char*)d_ws + WS_CNT_BYTE_OFF);

    kp_loss_fused<<<NBLK, 256, 0, stream>>>(all_scores, gt_heatmap, keypoints,
                                            ws, done_cnt, out);
}